// Round 11
// baseline (457.409 us; speedup 1.0000x reference)
//
#include <hip/hip_runtime.h>
#include <hip/hip_bf16.h>

#define N_NODES 25000
#define N_EDGES 600000
#define ACT_NONE 0
#define ACT_RELU 1
#define ACT_LEAKY 2

typedef __bf16 bf16x8 __attribute__((ext_vector_type(8)));
typedef float f32x4 __attribute__((ext_vector_type(4)));
typedef unsigned short u16x8 __attribute__((ext_vector_type(8)));
typedef unsigned short u16x4 __attribute__((ext_vector_type(4)));
typedef short s16x4 __attribute__((ext_vector_type(4)));

__device__ __forceinline__ unsigned short f2bf(float x) {
    union { float f; unsigned int u; } v; v.f = x;
    unsigned int r = (v.u + 0x7fffu + ((v.u >> 16) & 1u)) >> 16;
    return (unsigned short)r;
}
__device__ __forceinline__ float bf2f(unsigned short b) {
    union { float f; unsigned int u; } v; v.u = ((unsigned int)b) << 16;
    return v.f;
}

// ---------------------------------------------------------------------------
// CSR construction
// ---------------------------------------------------------------------------
__global__ __launch_bounds__(256) void hist_kernel(const int* __restrict__ dst,
                                                   int* __restrict__ deg, int E) {
    int e = blockIdx.x * 256 + threadIdx.x;
    if (e < E) atomicAdd(&deg[dst[e]], 1);
}

// wave-shuffle scan: 3 barriers per 1024-chunk
__global__ __launch_bounds__(1024) void scan_kernel(const int* __restrict__ deg,
                                                    int* __restrict__ off,
                                                    int* __restrict__ cursor, int n) {
    __shared__ int wsum[16];
    int t = threadIdx.x, w = t >> 6, l = t & 63;
    int carry = 0;
    for (int base = 0; base < n; base += 1024) {
        int v = (base + t < n) ? deg[base + t] : 0;
        int x = v;
        #pragma unroll
        for (int d = 1; d < 64; d <<= 1) {
            int y = __shfl_up(x, d);
            if (l >= d) x += y;
        }
        if (l == 63) wsum[w] = x;
        __syncthreads();
        if (w == 0 && l < 16) {
            int s = wsum[l];
            #pragma unroll
            for (int d = 1; d < 16; d <<= 1) {
                int y = __shfl_up(s, d);
                if (l >= d) s += y;
            }
            wsum[l] = s;
        }
        __syncthreads();
        int woff = (w > 0) ? wsum[w - 1] : 0;
        int excl = x + woff - v;
        if (base + t < n) {
            off[base + t] = carry + excl;
            cursor[base + t] = carry + excl;
        }
        int total = wsum[15];
        __syncthreads();
        carry += total;
    }
    if (t == 0) off[n] = carry;
}

__global__ __launch_bounds__(256) void scatter_kernel(const int* __restrict__ src,
                                                      const int* __restrict__ dst,
                                                      int* __restrict__ cursor,
                                                      int* __restrict__ csr_src, int E) {
    int e = blockIdx.x * 256 + threadIdx.x;
    if (e < E) {
        int d = dst[e];
        int pos = atomicAdd(&cursor[d], 1);
        csr_src[pos] = src[e];
    }
}

// ---------------------------------------------------------------------------
// fp32 -> bf16 hi/lo pair conversion (single large array)
// ---------------------------------------------------------------------------
__global__ __launch_bounds__(256) void convert_kernel(const float* __restrict__ src,
                                                      unsigned short* __restrict__ hi,
                                                      unsigned short* __restrict__ lo, int n) {
    int i = blockIdx.x * 256 + threadIdx.x;
    if (i < n) {
        float x = src[i];
        unsigned short h = f2bf(x);
        hi[i] = h;
        lo[i] = f2bf(x - bf2f(h));
    }
}

// batched conversion for the 10 weight matrices: blockIdx.y = segment
struct CvtBatch {
    const float* src[10];
    unsigned short* hi[10];
    unsigned short* lo[10];
    int count[10];
};
__global__ __launch_bounds__(256) void convert_batch_kernel(CvtBatch b) {
    int seg = blockIdx.y;
    int n = b.count[seg];
    int i = blockIdx.x * 256 + threadIdx.x;
    if (i >= n) return;
    float x = b.src[seg][i];
    unsigned short h = f2bf(x);
    b.hi[seg][i] = h;
    b.lo[seg][i] = f2bf(x - bf2f(h));
}

// ---------------------------------------------------------------------------
// SAGE mean aggregation over int16-quantized rows (per-64col-quarter scales)
// wave per node, 4-deep ILP
// ---------------------------------------------------------------------------
__global__ __launch_bounds__(256) void sage_mean_kernel(const short* __restrict__ qt,
                                                        const float* __restrict__ qs4,
                                                        const int* __restrict__ off,
                                                        const int* __restrict__ csr_src,
                                                        unsigned short* __restrict__ mh,
                                                        unsigned short* __restrict__ ml) {
    int node = blockIdx.x * 4 + (threadIdx.x >> 6);
    if (node >= N_NODES) return;
    int lane = threadIdx.x & 63;
    int qidx = lane >> 4;                       // this lane's 64-col quarter
    int s0 = off[node], s1 = off[node + 1];
    f32x4 acc0 = {0.f, 0.f, 0.f, 0.f}, acc1 = {0.f, 0.f, 0.f, 0.f};
    f32x4 acc2 = {0.f, 0.f, 0.f, 0.f}, acc3 = {0.f, 0.f, 0.f, 0.f};
    long loff = (long)lane * 4;
    int e = s0;
    for (; e + 4 <= s1; e += 4) {
        int iA = csr_src[e], iB = csr_src[e + 1], iC = csr_src[e + 2], iD = csr_src[e + 3];
        s16x4 qa = *(const s16x4*)&qt[(long)iA * 256 + loff];
        s16x4 qb = *(const s16x4*)&qt[(long)iB * 256 + loff];
        s16x4 qc = *(const s16x4*)&qt[(long)iC * 256 + loff];
        s16x4 qd = *(const s16x4*)&qt[(long)iD * 256 + loff];
        float sa = qs4[(long)iA * 4 + qidx], sb = qs4[(long)iB * 4 + qidx];
        float sc = qs4[(long)iC * 4 + qidx], sd = qs4[(long)iD * 4 + qidx];
        #pragma unroll
        for (int j = 0; j < 4; ++j) {
            acc0[j] += sa * (float)qa[j];
            acc1[j] += sb * (float)qb[j];
            acc2[j] += sc * (float)qc[j];
            acc3[j] += sd * (float)qd[j];
        }
    }
    for (; e < s1; ++e) {
        int iA = csr_src[e];
        s16x4 qa = *(const s16x4*)&qt[(long)iA * 256 + loff];
        float sa = qs4[(long)iA * 4 + qidx];
        #pragma unroll
        for (int j = 0; j < 4; ++j) acc0[j] += sa * (float)qa[j];
    }
    float inv = 1.0f / fmaxf((float)(s1 - s0), 1.0f);
    f32x4 m = ((acc0 + acc1) + (acc2 + acc3)) * inv;
    u16x4 hb, lb;
    #pragma unroll
    for (int j = 0; j < 4; ++j) {
        unsigned short hv = f2bf(m[j]);
        hb[j] = hv;
        lb[j] = f2bf(m[j] - bf2f(hv));
    }
    long base = (long)node * 256 + loff;
    *(u16x4*)&mh[base] = hb;
    *(u16x4*)&ml[base] = lb;
}

// ---------------------------------------------------------------------------
// MFMA split-bf16 dual GEMM, BM=BO=128, BK=32, TRUE double-buffer:
//   STAGE(t+1) -> s_waitcnt vmcnt(8) (counted: only current tile's 8 older
//   loads must land; next tile's 8 stay in flight across the barrier) ->
//   raw s_barrier -> sched_barrier(0) fence -> ds_read + 48 MFMA -> s_barrier.
//   (r7 failed because __syncthreads emits vmcnt(0), draining the prefetch.)
// LDS 2 x 32 KB = 64 KB -> 2 blocks/CU. r6-verified swizzle (0 conflicts).
// Epilogue can emit f32 (Cf), bf16 pair (Ch/Cl), int16+quarter-scale (Cq/Cqs).
// ---------------------------------------------------------------------------
__global__ __launch_bounds__(256, 2) void gemm_mfma_kernel(
    const unsigned short* __restrict__ A1h, const unsigned short* __restrict__ A1l,
    const unsigned short* __restrict__ W1h, const unsigned short* __restrict__ W1l,
    const unsigned short* __restrict__ A2h, const unsigned short* __restrict__ A2l,
    const unsigned short* __restrict__ W2h, const unsigned short* __restrict__ W2l,
    const float* __restrict__ bias,
    float* __restrict__ Cf, unsigned short* __restrict__ Ch, unsigned short* __restrict__ Cl,
    short* __restrict__ Cq, float* __restrict__ Cqs,
    int M, int K, int O, int act)
{
    __shared__ unsigned short sAh[2][128][32];
    __shared__ unsigned short sAl[2][128][32];
    __shared__ unsigned short sWh[2][128][32];
    __shared__ unsigned short sWl[2][128][32];

    int tid = threadIdx.x;
    int row0 = blockIdx.x * 128;
    int col0 = blockIdx.y * 128;
    int wid = tid >> 6, lane = tid & 63;
    int wm = (wid >> 1) * 64, wo = (wid & 1) * 64;
    int fr = lane & 15, qk = lane >> 4;
    int rr = lane >> 2, qq = lane & 3;   // staging: lane -> lds row rb+rr, chunk qq

    const int nt1 = K >> 5;
    const int nt  = (A2h != nullptr) ? (nt1 << 1) : nt1;

    f32x4 acc[4][4] = {};

    auto STAGE = [&](int buf, int t) {
        const unsigned short *Ah, *Al, *Wh, *Wl;
        int k0;
        if (t < nt1) { Ah = A1h; Al = A1l; Wh = W1h; Wl = W1l; k0 = t << 5; }
        else         { Ah = A2h; Al = A2l; Wh = W2h; Wl = W2l; k0 = (t - nt1) << 5; }
        #pragma unroll
        for (int i = 0; i < 2; ++i) {
            int rb = wid * 32 + i * 16;          // wave-uniform LDS row base
            int r = rb + rr;                     // this lane's row
            int gc = ((qq + (r >> 1)) & 3) * 8;  // swizzled global chunk col
            long ar = (long)(row0 + r);
            if (ar > M - 1) ar = M - 1;          // clamp; masked at C-write
            long wr = (long)(col0 + r);
            __builtin_amdgcn_global_load_lds(
                (const __attribute__((address_space(1))) unsigned int*)(Ah + ar * K + k0 + gc),
                (__attribute__((address_space(3))) unsigned int*)&sAh[buf][rb][0], 16, 0, 0);
            __builtin_amdgcn_global_load_lds(
                (const __attribute__((address_space(1))) unsigned int*)(Al + ar * K + k0 + gc),
                (__attribute__((address_space(3))) unsigned int*)&sAl[buf][rb][0], 16, 0, 0);
            __builtin_amdgcn_global_load_lds(
                (const __attribute__((address_space(1))) unsigned int*)(Wh + wr * K + k0 + gc),
                (__attribute__((address_space(3))) unsigned int*)&sWh[buf][rb][0], 16, 0, 0);
            __builtin_amdgcn_global_load_lds(
                (const __attribute__((address_space(1))) unsigned int*)(Wl + wr * K + k0 + gc),
                (__attribute__((address_space(3))) unsigned int*)&sWl[buf][rb][0], 16, 0, 0);
        }
    };

    STAGE(0, 0);   // 8 loads in flight

    for (int t = 0; t < nt; ++t) {
        int cur = t & 1;
        if (t + 1 < nt) {
            STAGE(cur ^ 1, t + 1);                      // +8 loads (next tile)
            asm volatile("s_waitcnt vmcnt(8)" ::: "memory");  // cur tile's 8 done
        } else {
            asm volatile("s_waitcnt vmcnt(0)" ::: "memory");  // last tile: drain
        }
        __builtin_amdgcn_s_barrier();                   // all waves: buf[cur] ready
        __builtin_amdgcn_sched_barrier(0);              // fence ds_reads below barrier

        bf16x8 ah[4], al[4], bh[4], bl[4];
        #pragma unroll
        for (int i = 0; i < 4; ++i) {
            int rowA = wm + i * 16 + fr;
            int offA = rowA * 32 + 8 * ((qk - (rowA >> 1)) & 3);
            ah[i] = *(const bf16x8*)(&sAh[cur][0][0] + offA);
            al[i] = *(const bf16x8*)(&sAl[cur][0][0] + offA);
            int rowB = wo + i * 16 + fr;
            int offB = rowB * 32 + 8 * ((qk - (rowB >> 1)) & 3);
            bh[i] = *(const bf16x8*)(&sWh[cur][0][0] + offB);
            bl[i] = *(const bf16x8*)(&sWl[cur][0][0] + offB);
        }
        #pragma unroll
        for (int i = 0; i < 4; ++i) {
            #pragma unroll
            for (int j = 0; j < 4; ++j) {
                acc[i][j] = __builtin_amdgcn_mfma_f32_16x16x32_bf16(ah[i], bh[j], acc[i][j], 0, 0, 0);
                acc[i][j] = __builtin_amdgcn_mfma_f32_16x16x32_bf16(ah[i], bl[j], acc[i][j], 0, 0, 0);
                acc[i][j] = __builtin_amdgcn_mfma_f32_16x16x32_bf16(al[i], bh[j], acc[i][j], 0, 0, 0);
            }
        }
        __builtin_amdgcn_s_barrier();   // reads of buf[cur] consumed before overwrite
    }

    // epilogue: C/D layout col=lane&15, row=(lane>>4)*4+reg  [m89-verified]
    int rgrp = (lane >> 4) * 4;
    int cl_ = lane & 15;
    int quarter = (col0 + wo) >> 6;
    #pragma unroll
    for (int i = 0; i < 4; ++i) {
        float bv[4];
        #pragma unroll
        for (int j = 0; j < 4; ++j) bv[j] = bias[col0 + wo + j * 16 + cl_];
        #pragma unroll
        for (int r = 0; r < 4; ++r) {
            int grow = row0 + wm + i * 16 + rgrp + r;
            float vv[4];
            float m = 0.0f;
            #pragma unroll
            for (int j = 0; j < 4; ++j) {
                float v = acc[i][j][r] + bv[j];
                if (act == ACT_RELU)       v = fmaxf(v, 0.0f);
                else if (act == ACT_LEAKY) v = (v > 0.0f) ? v : 0.01f * v;
                vv[j] = v;
                m = fmaxf(m, fabsf(v));
            }
            float qinv = 0.0f;
            if (Cq) {
                // 16-lane reduce over this row's quarter (lanes share lane>>4)
                #pragma unroll
                for (int d = 1; d < 16; d <<= 1) m = fmaxf(m, __shfl_xor(m, d));
                qinv = (m > 0.0f) ? 32767.0f / m : 0.0f;
            }
            bool ok = grow < M;
            #pragma unroll
            for (int j = 0; j < 4; ++j) {
                int gcol = col0 + wo + j * 16 + cl_;
                long idx = (long)grow * O + gcol;
                if (ok) {
                    float v = vv[j];
                    if (Cf) Cf[idx] = v;
                    if (Ch) {
                        unsigned short hbits = f2bf(v);
                        Ch[idx] = hbits;
                        Cl[idx] = f2bf(v - bf2f(hbits));
                    }
                    if (Cq) Cq[idx] = (short)(int)rintf(v * qinv);
                }
            }
            if (Cq && ok && cl_ == 0)
                Cqs[(long)grow * 4 + quarter] = (m > 0.0f) ? m / 32767.0f : 0.0f;
        }
    }
}

// ---------------------------------------------------------------------------
// Per-node edge-MLP dot products: nodeDot[n] = {dL96, dR96, dL32, dR32}
// ---------------------------------------------------------------------------
__global__ __launch_bounds__(256) void node_dots_kernel(const float* __restrict__ h,
                                                        const float* __restrict__ w96,
                                                        const float* __restrict__ w32,
                                                        float* __restrict__ nodeDot) {
    int node = blockIdx.x * 4 + (threadIdx.x >> 6);
    if (node >= N_NODES) return;
    int lane = threadIdx.x & 63;
    const float* row = h + (long)node * 128;
    float h0 = row[lane];
    float h1 = row[64 + lane];
    float pL96 = h0 * w96[lane];
    float pR96 = h0 * w96[96 + lane];
    float pL32 = 0.0f, pR32 = 0.0f;
    if (lane < 32) {
        pL96 += h1 * w96[64 + lane];
        pR96 += h1 * w96[160 + lane];
    } else {
        int k = lane - 32;
        pL32 = h1 * w32[k];
        pR32 = h1 * w32[32 + k];
    }
    #pragma unroll
    for (int m = 32; m > 0; m >>= 1) {
        pL96 += __shfl_xor(pL96, m);
        pR96 += __shfl_xor(pR96, m);
        pL32 += __shfl_xor(pL32, m);
        pR32 += __shfl_xor(pR32, m);
    }
    if (lane == 0) {
        f32x4 v = {pL96, pR96, pL32, pR32};
        *(f32x4*)&nodeDot[(long)node * 4] = v;
    }
}

// ---------------------------------------------------------------------------
// Fused per-edge affinity + 48-group mean: one thread per output group
// ---------------------------------------------------------------------------
__global__ __launch_bounds__(256) void edge_group_kernel(const float* __restrict__ nodeDot,
                                                         const int* __restrict__ src,
                                                         const int* __restrict__ dst,
                                                         const float* __restrict__ eattr,
                                                         const float* __restrict__ b96,
                                                         const float* __restrict__ b32,
                                                         float* __restrict__ out, int G) {
    int g = blockIdx.x * 256 + threadIdx.x;
    if (g >= G) return;
    float bb96 = b96[0], bb32 = b32[0];
    int base = g * 48;
    float s = 0.0f;
    #pragma unroll 4
    for (int k = 0; k < 48; ++k) {
        int e = base + k;
        f32x4 a = *(const f32x4*)&nodeDot[(long)src[e] * 4];
        f32x4 b = *(const f32x4*)&nodeDot[(long)dst[e] * 4];
        float f96  = fmaxf(a[0] + b[1] + bb96, 0.0f);
        float f32v = fmaxf(a[2] + b[3] + bb32, 0.0f);
        s += f96 * eattr[e] + f32v;
    }
    out[g] = s * (1.0f / 48.0f);
}

// ---------------------------------------------------------------------------
extern "C" void kernel_launch(void* const* d_in, const int* in_sizes, int n_in,
                              void* d_out, int out_size, void* d_ws, size_t ws_size,
                              hipStream_t stream) {
    const float* x         = (const float*)d_in[0];
    const int*   edge_idx  = (const int*)d_in[1];
    const float* edge_attr = (const float*)d_in[2];
    const float* prelin_w  = (const float*)d_in[4];
    const float* prelin_b  = (const float*)d_in[5];
    const float* conv1_lw  = (const float*)d_in[6];
    const float* conv1_lb  = (const float*)d_in[7];
    const float* conv1_rw  = (const float*)d_in[8];
    const float* conv2_lw  = (const float*)d_in[9];
    const float* conv2_lb  = (const float*)d_in[10];
    const float* conv2_rw  = (const float*)d_in[11];
    const float* conv3_lw  = (const float*)d_in[12];
    const float* conv3_lb  = (const float*)d_in[13];
    const float* conv3_rw  = (const float*)d_in[14];
    const float* hh1_w     = (const float*)d_in[15];
    const float* hh1_b     = (const float*)d_in[16];
    const float* hh2_w     = (const float*)d_in[17];
    const float* hh2_b     = (const float*)d_in[18];
    const float* oo_w      = (const float*)d_in[19];
    const float* oo_b      = (const float*)d_in[20];
    const float* lin96_w   = (const float*)d_in[21];
    const float* lin96_b   = (const float*)d_in[22];
    const float* lin32_w   = (const float*)d_in[23];
    const float* lin32_b   = (const float*)d_in[24];

    const int* src = edge_idx;
    const int* dst = edge_idx + N_EDGES;

    // ---- workspace carve-up ----
    char* wsp = (char*)d_ws;
    size_t used = 0;
    auto alloc = [&](size_t bytes) -> char* {
        char* r = wsp;
        size_t pad = (bytes + 255) & ~(size_t)255;
        wsp += pad; used += pad;
        return r;
    };
    float* bufF = (float*)alloc((size_t)N_NODES * 256 * 4);
    unsigned short* P0h = (unsigned short*)alloc((size_t)N_NODES * 256 * 2);
    unsigned short* P0l = (unsigned short*)alloc((size_t)N_NODES * 256 * 2);
    unsigned short* P1h = (unsigned short*)alloc((size_t)N_NODES * 256 * 2);
    unsigned short* P1l = (unsigned short*)alloc((size_t)N_NODES * 256 * 2);
    unsigned short* P2h = (unsigned short*)alloc((size_t)N_NODES * 256 * 2);
    unsigned short* P2l = (unsigned short*)alloc((size_t)N_NODES * 256 * 2);
    short* qtab    = (short*)alloc((size_t)N_NODES * 256 * 2);
    float* qsc4    = (float*)alloc((size_t)N_NODES * 4 * 4);
    float* nodeDot = (float*)alloc((size_t)N_NODES * 4 * 4);
    int* deg       = (int*)alloc((size_t)N_NODES * 4);
    int* off       = (int*)alloc((size_t)(N_NODES + 1) * 4);
    int* cursor    = (int*)alloc((size_t)N_NODES * 4);
    int* csr_src   = (int*)alloc((size_t)N_EDGES * 4);

    struct WP { unsigned short *h, *l; };
    auto wpair = [&](int n) -> WP {
        WP w; w.h = (unsigned short*)alloc((size_t)n * 2);
        w.l = (unsigned short*)alloc((size_t)n * 2); return w;
    };
    WP w_pre = wpair(256 * 128);
    WP w_c1l = wpair(256 * 256), w_c1r = wpair(256 * 256);
    WP w_c2l = wpair(256 * 256), w_c2r = wpair(256 * 256);
    WP w_c3l = wpair(128 * 256), w_c3r = wpair(128 * 256);
    WP w_h1  = wpair(256 * 256), w_h2 = wpair(256 * 256);
    WP w_oo  = wpair(128 * 128);

    if (used > ws_size) return;  // loud failure rather than silent corruption

    const int EB = (N_EDGES + 255) / 256;
    const int MB = (N_NODES + 127) / 128;  // 196
    const int NB4 = (N_NODES + 3) / 4;     // 6250 (wave-per-node kernels)

    // CSR build
    (void)hipMemsetAsync(deg, 0, N_NODES * sizeof(int), stream);
    hist_kernel<<<EB, 256, 0, stream>>>(dst, deg, N_EDGES);
    scan_kernel<<<1, 1024, 0, stream>>>(deg, off, cursor, N_NODES);
    scatter_kernel<<<EB, 256, 0, stream>>>(src, dst, cursor, csr_src, N_EDGES);

    // conversions: x separately, 10 weights in ONE batched launch
    convert_kernel<<<((N_NODES * 128) + 255) / 256, 256, 0, stream>>>(x, P0h, P0l, N_NODES * 128);
    CvtBatch cb;
    const float* wsrc[10] = {prelin_w, conv1_lw, conv1_rw, conv2_lw, conv2_rw,
                             conv3_lw, conv3_rw, hh1_w, hh2_w, oo_w};
    WP wdst[10] = {w_pre, w_c1l, w_c1r, w_c2l, w_c2r, w_c3l, w_c3r, w_h1, w_h2, w_oo};
    int wcnt[10] = {256 * 128, 256 * 256, 256 * 256, 256 * 256, 256 * 256,
                    128 * 256, 128 * 256, 256 * 256, 256 * 256, 128 * 128};
    for (int i = 0; i < 10; ++i) {
        cb.src[i] = wsrc[i]; cb.hi[i] = wdst[i].h; cb.lo[i] = wdst[i].l; cb.count[i] = wcnt[i];
    }
    convert_batch_kernel<<<dim3((65536 + 255) / 256, 10), 256, 0, stream>>>(cb);

    // prelin: h1 = relu(x W^T + b) -> P1 pair + int16/scale (fused quant)
    gemm_mfma_kernel<<<dim3(MB, 2), 256, 0, stream>>>(
        P0h, P0l, w_pre.h, w_pre.l, nullptr, nullptr, nullptr, nullptr,
        prelin_b, nullptr, P1h, P1l, qtab, qsc4, N_NODES, 128, 256, ACT_RELU);

    // conv1 + hh1
    sage_mean_kernel<<<NB4, 256, 0, stream>>>(qtab, qsc4, off, csr_src, P2h, P2l);
    gemm_mfma_kernel<<<dim3(MB, 2), 256, 0, stream>>>(
        P2h, P2l, w_c1l.h, w_c1l.l, P1h, P1l, w_c1r.h, w_c1r.l,
        conv1_lb, nullptr, P0h, P0l, nullptr, nullptr, N_NODES, 256, 256, ACT_RELU);
    gemm_mfma_kernel<<<dim3(MB, 2), 256, 0, stream>>>(
        P0h, P0l, w_h1.h, w_h1.l, nullptr, nullptr, nullptr, nullptr,
        hh1_b, nullptr, P1h, P1l, qtab, qsc4, N_NODES, 256, 256, ACT_LEAKY);

    // conv2 + hh2
    sage_mean_kernel<<<NB4, 256, 0, stream>>>(qtab, qsc4, off, csr_src, P2h, P2l);
    gemm_mfma_kernel<<<dim3(MB, 2), 256, 0, stream>>>(
        P2h, P2l, w_c2l.h, w_c2l.l, P1h, P1l, w_c2r.h, w_c2r.l,
        conv2_lb, nullptr, P0h, P0l, nullptr, nullptr, N_NODES, 256, 256, ACT_RELU);
    gemm_mfma_kernel<<<dim3(MB, 2), 256, 0, stream>>>(
        P0h, P0l, w_h2.h, w_h2.l, nullptr, nullptr, nullptr, nullptr,
        hh2_b, nullptr, P1h, P1l, qtab, qsc4, N_NODES, 256, 256, ACT_LEAKY);

    // conv3 (O=128) + oo
    sage_mean_kernel<<<NB4, 256, 0, stream>>>(qtab, qsc4, off, csr_src, P2h, P2l);
    gemm_mfma_kernel<<<dim3(MB, 1), 256, 0, stream>>>(
        P2h, P2l, w_c3l.h, w_c3l.l, P1h, P1l, w_c3r.h, w_c3r.l,
        conv3_lb, nullptr, P0h, P0l, nullptr, nullptr, N_NODES, 256, 128, ACT_RELU);
    gemm_mfma_kernel<<<dim3(MB, 1), 256, 0, stream>>>(
        P0h, P0l, w_oo.h, w_oo.l, nullptr, nullptr, nullptr, nullptr,
        oo_b, bufF, nullptr, nullptr, nullptr, nullptr, N_NODES, 128, 128, ACT_LEAKY);

    // per-node dots -> fused per-edge affinity + 48-group mean
    node_dots_kernel<<<NB4, 256, 0, stream>>>(bufF, lin96_w, lin32_w, nodeDot);
    const int G = N_EDGES / 48;
    edge_group_kernel<<<(G + 255) / 256, 256, 0, stream>>>(
        nodeDot, src, dst, edge_attr, lin96_b, lin32_b, (float*)d_out, G);
}

// Round 12
// 440.455 us; speedup vs baseline: 1.0385x; 1.0385x over previous
//
#include <hip/hip_runtime.h>
#include <hip/hip_bf16.h>

#define N_NODES 25000
#define N_EDGES 600000
#define ACT_NONE 0
#define ACT_RELU 1
#define ACT_LEAKY 2

typedef __bf16 bf16x8 __attribute__((ext_vector_type(8)));
typedef float f32x4 __attribute__((ext_vector_type(4)));
typedef unsigned short u16x8 __attribute__((ext_vector_type(8)));
typedef unsigned short u16x4 __attribute__((ext_vector_type(4)));
typedef short s16x4 __attribute__((ext_vector_type(4)));

__device__ __forceinline__ unsigned short f2bf(float x) {
    union { float f; unsigned int u; } v; v.f = x;
    unsigned int r = (v.u + 0x7fffu + ((v.u >> 16) & 1u)) >> 16;
    return (unsigned short)r;
}
__device__ __forceinline__ float bf2f(unsigned short b) {
    union { float f; unsigned int u; } v; v.u = ((unsigned int)b) << 16;
    return v.f;
}

// ---------------------------------------------------------------------------
// CSR construction
// ---------------------------------------------------------------------------
__global__ __launch_bounds__(256) void hist_kernel(const int* __restrict__ dst,
                                                   int* __restrict__ deg, int E) {
    int e = blockIdx.x * 256 + threadIdx.x;
    if (e < E) atomicAdd(&deg[dst[e]], 1);
}

// wave-shuffle scan: 3 barriers per 1024-chunk
__global__ __launch_bounds__(1024) void scan_kernel(const int* __restrict__ deg,
                                                    int* __restrict__ off,
                                                    int* __restrict__ cursor, int n) {
    __shared__ int wsum[16];
    int t = threadIdx.x, w = t >> 6, l = t & 63;
    int carry = 0;
    for (int base = 0; base < n; base += 1024) {
        int v = (base + t < n) ? deg[base + t] : 0;
        int x = v;
        #pragma unroll
        for (int d = 1; d < 64; d <<= 1) {
            int y = __shfl_up(x, d);
            if (l >= d) x += y;
        }
        if (l == 63) wsum[w] = x;
        __syncthreads();
        if (w == 0 && l < 16) {
            int s = wsum[l];
            #pragma unroll
            for (int d = 1; d < 16; d <<= 1) {
                int y = __shfl_up(s, d);
                if (l >= d) s += y;
            }
            wsum[l] = s;
        }
        __syncthreads();
        int woff = (w > 0) ? wsum[w - 1] : 0;
        int excl = x + woff - v;
        if (base + t < n) {
            off[base + t] = carry + excl;
            cursor[base + t] = carry + excl;
        }
        int total = wsum[15];
        __syncthreads();
        carry += total;
    }
    if (t == 0) off[n] = carry;
}

__global__ __launch_bounds__(256) void scatter_kernel(const int* __restrict__ src,
                                                      const int* __restrict__ dst,
                                                      int* __restrict__ cursor,
                                                      int* __restrict__ csr_src, int E) {
    int e = blockIdx.x * 256 + threadIdx.x;
    if (e < E) {
        int d = dst[e];
        int pos = atomicAdd(&cursor[d], 1);
        csr_src[pos] = src[e];
    }
}

// ---------------------------------------------------------------------------
// fp32 -> bf16 hi/lo pair conversion (single large array)
// ---------------------------------------------------------------------------
__global__ __launch_bounds__(256) void convert_kernel(const float* __restrict__ src,
                                                      unsigned short* __restrict__ hi,
                                                      unsigned short* __restrict__ lo, int n) {
    int i = blockIdx.x * 256 + threadIdx.x;
    if (i < n) {
        float x = src[i];
        unsigned short h = f2bf(x);
        hi[i] = h;
        lo[i] = f2bf(x - bf2f(h));
    }
}

// batched conversion for the 10 weight matrices: blockIdx.y = segment
struct CvtBatch {
    const float* src[10];
    unsigned short* hi[10];
    unsigned short* lo[10];
    int count[10];
};
__global__ __launch_bounds__(256) void convert_batch_kernel(CvtBatch b) {
    int seg = blockIdx.y;
    int n = b.count[seg];
    int i = blockIdx.x * 256 + threadIdx.x;
    if (i >= n) return;
    float x = b.src[seg][i];
    unsigned short h = f2bf(x);
    b.hi[seg][i] = h;
    b.lo[seg][i] = f2bf(x - bf2f(h));
}

// ---------------------------------------------------------------------------
// SAGE mean aggregation over int16-quantized rows (per-64col-quarter scales)
// wave per node, 4-deep ILP
// ---------------------------------------------------------------------------
__global__ __launch_bounds__(256) void sage_mean_kernel(const short* __restrict__ qt,
                                                        const float* __restrict__ qs4,
                                                        const int* __restrict__ off,
                                                        const int* __restrict__ csr_src,
                                                        unsigned short* __restrict__ mh,
                                                        unsigned short* __restrict__ ml) {
    int node = blockIdx.x * 4 + (threadIdx.x >> 6);
    if (node >= N_NODES) return;
    int lane = threadIdx.x & 63;
    int qidx = lane >> 4;                       // this lane's 64-col quarter
    int s0 = off[node], s1 = off[node + 1];
    f32x4 acc0 = {0.f, 0.f, 0.f, 0.f}, acc1 = {0.f, 0.f, 0.f, 0.f};
    f32x4 acc2 = {0.f, 0.f, 0.f, 0.f}, acc3 = {0.f, 0.f, 0.f, 0.f};
    long loff = (long)lane * 4;
    int e = s0;
    for (; e + 4 <= s1; e += 4) {
        int iA = csr_src[e], iB = csr_src[e + 1], iC = csr_src[e + 2], iD = csr_src[e + 3];
        s16x4 qa = *(const s16x4*)&qt[(long)iA * 256 + loff];
        s16x4 qb = *(const s16x4*)&qt[(long)iB * 256 + loff];
        s16x4 qc = *(const s16x4*)&qt[(long)iC * 256 + loff];
        s16x4 qd = *(const s16x4*)&qt[(long)iD * 256 + loff];
        float sa = qs4[(long)iA * 4 + qidx], sb = qs4[(long)iB * 4 + qidx];
        float sc = qs4[(long)iC * 4 + qidx], sd = qs4[(long)iD * 4 + qidx];
        #pragma unroll
        for (int j = 0; j < 4; ++j) {
            acc0[j] += sa * (float)qa[j];
            acc1[j] += sb * (float)qb[j];
            acc2[j] += sc * (float)qc[j];
            acc3[j] += sd * (float)qd[j];
        }
    }
    for (; e < s1; ++e) {
        int iA = csr_src[e];
        s16x4 qa = *(const s16x4*)&qt[(long)iA * 256 + loff];
        float sa = qs4[(long)iA * 4 + qidx];
        #pragma unroll
        for (int j = 0; j < 4; ++j) acc0[j] += sa * (float)qa[j];
    }
    float inv = 1.0f / fmaxf((float)(s1 - s0), 1.0f);
    f32x4 m = ((acc0 + acc1) + (acc2 + acc3)) * inv;
    u16x4 hb, lb;
    #pragma unroll
    for (int j = 0; j < 4; ++j) {
        unsigned short hv = f2bf(m[j]);
        hb[j] = hv;
        lb[j] = f2bf(m[j] - bf2f(hv));
    }
    long base = (long)node * 256 + loff;
    *(u16x4*)&mh[base] = hb;
    *(u16x4*)&ml[base] = lb;
}

// ---------------------------------------------------------------------------
// MFMA split-bf16 dual GEMM, BM=BO=128, BK=64, merged dual-K loop
// (r10 structure -- best measured).  Epilogue can emit any of: f32 (Cf),
// bf16 hi/lo pair (Ch/Cl), int16 + per-64col-quarter scale (Cq/Cqs), and
// -- new -- fused edge-MLP node dots (w96d/w32d/nodeDotG; only valid when
// O==128, single col-block: each block holds every row's full 128 cols).
// Swizzle: r6-verified chunk rotation per 32-short half-row (0 conflicts).
// ---------------------------------------------------------------------------
__global__ __launch_bounds__(256, 2) void gemm_mfma_kernel(
    const unsigned short* __restrict__ A1h, const unsigned short* __restrict__ A1l,
    const unsigned short* __restrict__ W1h, const unsigned short* __restrict__ W1l,
    const unsigned short* __restrict__ A2h, const unsigned short* __restrict__ A2l,
    const unsigned short* __restrict__ W2h, const unsigned short* __restrict__ W2l,
    const float* __restrict__ bias,
    float* __restrict__ Cf, unsigned short* __restrict__ Ch, unsigned short* __restrict__ Cl,
    short* __restrict__ Cq, float* __restrict__ Cqs,
    const float* __restrict__ w96d, const float* __restrict__ w32d,
    float* __restrict__ nodeDotG,
    int M, int K, int O, int act)
{
    __shared__ unsigned short sAh[128][64];
    __shared__ unsigned short sAl[128][64];
    __shared__ unsigned short sWh[128][64];
    __shared__ unsigned short sWl[128][64];

    int tid = threadIdx.x;
    int row0 = blockIdx.x * 128;
    int col0 = blockIdx.y * 128;
    int wid = tid >> 6, lane = tid & 63;
    int wm = (wid >> 1) * 64, wo = (wid & 1) * 64;
    int fr = lane & 15, qk = lane >> 4;
    int rr = lane >> 3, qq = lane & 7;          // staging: 8 rows x 8 chunks
    int shalf = (qq >> 2) * 32, scq = qq & 3;   // chunk-in-half

    const int nt1 = K >> 6;
    const int nt  = (A2h != nullptr) ? (nt1 << 1) : nt1;

    f32x4 acc[4][4] = {};

    for (int t = 0; t < nt; ++t) {
        const unsigned short *Ah, *Al, *Wh, *Wl;
        int k0;
        if (t < nt1) { Ah = A1h; Al = A1l; Wh = W1h; Wl = W1l; k0 = t << 6; }
        else         { Ah = A2h; Al = A2l; Wh = W2h; Wl = W2l; k0 = (t - nt1) << 6; }

        #pragma unroll
        for (int i = 0; i < 4; ++i) {
            int rb = wid * 32 + i * 8;               // wave-uniform LDS row base
            int r  = rb + rr;                        // this lane's row
            int gs = shalf + ((scq + (r >> 1)) & 3) * 8;  // swizzled global shorts
            long ar = (long)(row0 + r); if (ar > M - 1) ar = M - 1;
            long wr = (long)(col0 + r);
            __builtin_amdgcn_global_load_lds(
                (const __attribute__((address_space(1))) unsigned int*)(Ah + ar * K + k0 + gs),
                (__attribute__((address_space(3))) unsigned int*)&sAh[rb][0], 16, 0, 0);
            __builtin_amdgcn_global_load_lds(
                (const __attribute__((address_space(1))) unsigned int*)(Al + ar * K + k0 + gs),
                (__attribute__((address_space(3))) unsigned int*)&sAl[rb][0], 16, 0, 0);
            __builtin_amdgcn_global_load_lds(
                (const __attribute__((address_space(1))) unsigned int*)(Wh + wr * K + k0 + gs),
                (__attribute__((address_space(3))) unsigned int*)&sWh[rb][0], 16, 0, 0);
            __builtin_amdgcn_global_load_lds(
                (const __attribute__((address_space(1))) unsigned int*)(Wl + wr * K + k0 + gs),
                (__attribute__((address_space(3))) unsigned int*)&sWl[rb][0], 16, 0, 0);
        }
        __syncthreads();   // vmcnt drain: tile ready

        #pragma unroll
        for (int kk = 0; kk < 2; ++kk) {
            bf16x8 ah[4], al[4], bh[4], bl[4];
            #pragma unroll
            for (int i = 0; i < 4; ++i) {
                int rowA = wm + i * 16 + fr;
                int offA = rowA * 64 + kk * 32 + 8 * ((qk - (rowA >> 1)) & 3);
                ah[i] = *(const bf16x8*)(&sAh[0][0] + offA);
                al[i] = *(const bf16x8*)(&sAl[0][0] + offA);
                int rowB = wo + i * 16 + fr;
                int offB = rowB * 64 + kk * 32 + 8 * ((qk - (rowB >> 1)) & 3);
                bh[i] = *(const bf16x8*)(&sWh[0][0] + offB);
                bl[i] = *(const bf16x8*)(&sWl[0][0] + offB);
            }
            #pragma unroll
            for (int i = 0; i < 4; ++i) {
                #pragma unroll
                for (int j = 0; j < 4; ++j) {
                    acc[i][j] = __builtin_amdgcn_mfma_f32_16x16x32_bf16(ah[i], bh[j], acc[i][j], 0, 0, 0);
                    acc[i][j] = __builtin_amdgcn_mfma_f32_16x16x32_bf16(ah[i], bl[j], acc[i][j], 0, 0, 0);
                    acc[i][j] = __builtin_amdgcn_mfma_f32_16x16x32_bf16(al[i], bh[j], acc[i][j], 0, 0, 0);
                }
            }
        }
        __syncthreads();   // protect single buffer before next stage
    }

    // epilogue: C/D layout col=lane&15, row=(lane>>4)*4+reg  [m89-verified]
    int rgrp = (lane >> 4) * 4;
    int cl_ = lane & 15;
    int quarter = (col0 + wo) >> 6;

    // fused node-dot weights for this thread's 4 columns (oo GEMM only)
    float wa96[4], wb96[4], wa32[4], wb32[4];
    if (nodeDotG) {
        #pragma unroll
        for (int j = 0; j < 4; ++j) {
            int c = wo + j * 16 + cl_;
            bool lo96 = c < 96;
            wa96[j] = lo96 ? w96d[c] : 0.0f;
            wb96[j] = lo96 ? w96d[96 + c] : 0.0f;
            wa32[j] = lo96 ? 0.0f : w32d[c - 96];
            wb32[j] = lo96 ? 0.0f : w32d[c - 64];   // 32 + (c - 96)
        }
    }

    #pragma unroll
    for (int i = 0; i < 4; ++i) {
        float bv[4];
        #pragma unroll
        for (int j = 0; j < 4; ++j) bv[j] = bias[col0 + wo + j * 16 + cl_];
        #pragma unroll
        for (int r = 0; r < 4; ++r) {
            int grow = row0 + wm + i * 16 + rgrp + r;
            float vv[4];
            float m = 0.0f;
            #pragma unroll
            for (int j = 0; j < 4; ++j) {
                float v = acc[i][j][r] + bv[j];
                if (act == ACT_RELU)       v = fmaxf(v, 0.0f);
                else if (act == ACT_LEAKY) v = (v > 0.0f) ? v : 0.01f * v;
                vv[j] = v;
                m = fmaxf(m, fabsf(v));
            }
            float qinv = 0.0f;
            if (Cq) {
                // 16-lane reduce over this row's quarter (lanes share lane>>4)
                #pragma unroll
                for (int d = 1; d < 16; d <<= 1) m = fmaxf(m, __shfl_xor(m, d));
                qinv = (m > 0.0f) ? 32767.0f / m : 0.0f;
            }
            bool ok = grow < M;
            #pragma unroll
            for (int j = 0; j < 4; ++j) {
                int gcol = col0 + wo + j * 16 + cl_;
                long idx = (long)grow * O + gcol;
                if (ok) {
                    float v = vv[j];
                    if (Cf) Cf[idx] = v;
                    if (Ch) {
                        unsigned short hbits = f2bf(v);
                        Ch[idx] = hbits;
                        Cl[idx] = f2bf(v - bf2f(hbits));
                    }
                    if (Cq) Cq[idx] = (short)(int)rintf(v * qinv);
                }
            }
            if (Cq && ok && cl_ == 0)
                Cqs[(long)grow * 4 + quarter] = (m > 0.0f) ? m / 32767.0f : 0.0f;

            if (nodeDotG) {
                float pL96 = vv[0]*wa96[0] + vv[1]*wa96[1] + vv[2]*wa96[2] + vv[3]*wa96[3];
                float pR96 = vv[0]*wb96[0] + vv[1]*wb96[1] + vv[2]*wb96[2] + vv[3]*wb96[3];
                float pL32 = vv[0]*wa32[0] + vv[1]*wa32[1] + vv[2]*wa32[2] + vv[3]*wa32[3];
                float pR32 = vv[0]*wb32[0] + vv[1]*wb32[1] + vv[2]*wb32[2] + vv[3]*wb32[3];
                #pragma unroll
                for (int d = 1; d < 16; d <<= 1) {
                    pL96 += __shfl_xor(pL96, d);
                    pR96 += __shfl_xor(pR96, d);
                    pL32 += __shfl_xor(pL32, d);
                    pR32 += __shfl_xor(pR32, d);
                }
                if (cl_ == 0) {
                    int rl = wm + i * 16 + rgrp + r;
                    f32x4 pv = {pL96, pR96, pL32, pR32};
                    ((f32x4*)&sAh[0][0])[rl * 2 + (wo >> 6)] = pv;   // reuse LDS
                }
            }
        }
    }

    if (nodeDotG) {
        __syncthreads();
        if (wo == 0) {                       // waves 0 and 2: one row per lane
            int rl = wm + lane;
            int grow = row0 + rl;
            if (grow < M) {
                f32x4 a = ((f32x4*)&sAh[0][0])[rl * 2 + 0];
                f32x4 b = ((f32x4*)&sAh[0][0])[rl * 2 + 1];
                f32x4 s = a + b;
                *(f32x4*)&nodeDotG[(long)grow * 4] = s;
            }
        }
    }
}

// ---------------------------------------------------------------------------
// Fused per-edge affinity + 48-group mean: one thread per output group
// ---------------------------------------------------------------------------
__global__ __launch_bounds__(256) void edge_group_kernel(const float* __restrict__ nodeDot,
                                                         const int* __restrict__ src,
                                                         const int* __restrict__ dst,
                                                         const float* __restrict__ eattr,
                                                         const float* __restrict__ b96,
                                                         const float* __restrict__ b32,
                                                         float* __restrict__ out, int G) {
    int g = blockIdx.x * 256 + threadIdx.x;
    if (g >= G) return;
    float bb96 = b96[0], bb32 = b32[0];
    int base = g * 48;
    float s = 0.0f;
    #pragma unroll 4
    for (int k = 0; k < 48; ++k) {
        int e = base + k;
        f32x4 a = *(const f32x4*)&nodeDot[(long)src[e] * 4];
        f32x4 b = *(const f32x4*)&nodeDot[(long)dst[e] * 4];
        float f96  = fmaxf(a[0] + b[1] + bb96, 0.0f);
        float f32v = fmaxf(a[2] + b[3] + bb32, 0.0f);
        s += f96 * eattr[e] + f32v;
    }
    out[g] = s * (1.0f / 48.0f);
}

// ---------------------------------------------------------------------------
extern "C" void kernel_launch(void* const* d_in, const int* in_sizes, int n_in,
                              void* d_out, int out_size, void* d_ws, size_t ws_size,
                              hipStream_t stream) {
    const float* x         = (const float*)d_in[0];
    const int*   edge_idx  = (const int*)d_in[1];
    const float* edge_attr = (const float*)d_in[2];
    const float* prelin_w  = (const float*)d_in[4];
    const float* prelin_b  = (const float*)d_in[5];
    const float* conv1_lw  = (const float*)d_in[6];
    const float* conv1_lb  = (const float*)d_in[7];
    const float* conv1_rw  = (const float*)d_in[8];
    const float* conv2_lw  = (const float*)d_in[9];
    const float* conv2_lb  = (const float*)d_in[10];
    const float* conv2_rw  = (const float*)d_in[11];
    const float* conv3_lw  = (const float*)d_in[12];
    const float* conv3_lb  = (const float*)d_in[13];
    const float* conv3_rw  = (const float*)d_in[14];
    const float* hh1_w     = (const float*)d_in[15];
    const float* hh1_b     = (const float*)d_in[16];
    const float* hh2_w     = (const float*)d_in[17];
    const float* hh2_b     = (const float*)d_in[18];
    const float* oo_w      = (const float*)d_in[19];
    const float* oo_b      = (const float*)d_in[20];
    const float* lin96_w   = (const float*)d_in[21];
    const float* lin96_b   = (const float*)d_in[22];
    const float* lin32_w   = (const float*)d_in[23];
    const float* lin32_b   = (const float*)d_in[24];

    const int* src = edge_idx;
    const int* dst = edge_idx + N_EDGES;

    // ---- workspace carve-up ----
    char* wsp = (char*)d_ws;
    size_t used = 0;
    auto alloc = [&](size_t bytes) -> char* {
        char* r = wsp;
        size_t pad = (bytes + 255) & ~(size_t)255;
        wsp += pad; used += pad;
        return r;
    };
    unsigned short* P0h = (unsigned short*)alloc((size_t)N_NODES * 256 * 2);
    unsigned short* P0l = (unsigned short*)alloc((size_t)N_NODES * 256 * 2);
    unsigned short* P1h = (unsigned short*)alloc((size_t)N_NODES * 256 * 2);
    unsigned short* P1l = (unsigned short*)alloc((size_t)N_NODES * 256 * 2);
    unsigned short* P2h = (unsigned short*)alloc((size_t)N_NODES * 256 * 2);
    unsigned short* P2l = (unsigned short*)alloc((size_t)N_NODES * 256 * 2);
    short* qtab    = (short*)alloc((size_t)N_NODES * 256 * 2);
    float* qsc4    = (float*)alloc((size_t)N_NODES * 4 * 4);
    float* nodeDot = (float*)alloc((size_t)N_NODES * 4 * 4);
    int* deg       = (int*)alloc((size_t)N_NODES * 4);
    int* off       = (int*)alloc((size_t)(N_NODES + 1) * 4);
    int* cursor    = (int*)alloc((size_t)N_NODES * 4);
    int* csr_src   = (int*)alloc((size_t)N_EDGES * 4);

    struct WP { unsigned short *h, *l; };
    auto wpair = [&](int n) -> WP {
        WP w; w.h = (unsigned short*)alloc((size_t)n * 2);
        w.l = (unsigned short*)alloc((size_t)n * 2); return w;
    };
    WP w_pre = wpair(256 * 128);
    WP w_c1l = wpair(256 * 256), w_c1r = wpair(256 * 256);
    WP w_c2l = wpair(256 * 256), w_c2r = wpair(256 * 256);
    WP w_c3l = wpair(128 * 256), w_c3r = wpair(128 * 256);
    WP w_h1  = wpair(256 * 256), w_h2 = wpair(256 * 256);
    WP w_oo  = wpair(128 * 128);

    if (used > ws_size) return;  // loud failure rather than silent corruption

    const int EB = (N_EDGES + 255) / 256;
    const int MB = (N_NODES + 127) / 128;  // 196
    const int NB4 = (N_NODES + 3) / 4;     // 6250 (wave-per-node kernels)

    // CSR build
    (void)hipMemsetAsync(deg, 0, N_NODES * sizeof(int), stream);
    hist_kernel<<<EB, 256, 0, stream>>>(dst, deg, N_EDGES);
    scan_kernel<<<1, 1024, 0, stream>>>(deg, off, cursor, N_NODES);
    scatter_kernel<<<EB, 256, 0, stream>>>(src, dst, cursor, csr_src, N_EDGES);

    // conversions: x separately, 10 weights in ONE batched launch
    convert_kernel<<<((N_NODES * 128) + 255) / 256, 256, 0, stream>>>(x, P0h, P0l, N_NODES * 128);
    CvtBatch cb;
    const float* wsrc[10] = {prelin_w, conv1_lw, conv1_rw, conv2_lw, conv2_rw,
                             conv3_lw, conv3_rw, hh1_w, hh2_w, oo_w};
    WP wdst[10] = {w_pre, w_c1l, w_c1r, w_c2l, w_c2r, w_c3l, w_c3r, w_h1, w_h2, w_oo};
    int wcnt[10] = {256 * 128, 256 * 256, 256 * 256, 256 * 256, 256 * 256,
                    128 * 256, 128 * 256, 256 * 256, 256 * 256, 128 * 128};
    for (int i = 0; i < 10; ++i) {
        cb.src[i] = wsrc[i]; cb.hi[i] = wdst[i].h; cb.lo[i] = wdst[i].l; cb.count[i] = wcnt[i];
    }
    convert_batch_kernel<<<dim3((65536 + 255) / 256, 10), 256, 0, stream>>>(cb);

    // prelin: h1 = relu(x W^T + b) -> P1 pair + int16/scale (fused quant)
    gemm_mfma_kernel<<<dim3(MB, 2), 256, 0, stream>>>(
        P0h, P0l, w_pre.h, w_pre.l, nullptr, nullptr, nullptr, nullptr,
        prelin_b, nullptr, P1h, P1l, qtab, qsc4,
        nullptr, nullptr, nullptr, N_NODES, 128, 256, ACT_RELU);

    // conv1 + hh1
    sage_mean_kernel<<<NB4, 256, 0, stream>>>(qtab, qsc4, off, csr_src, P2h, P2l);
    gemm_mfma_kernel<<<dim3(MB, 2), 256, 0, stream>>>(
        P2h, P2l, w_c1l.h, w_c1l.l, P1h, P1l, w_c1r.h, w_c1r.l,
        conv1_lb, nullptr, P0h, P0l, nullptr, nullptr,
        nullptr, nullptr, nullptr, N_NODES, 256, 256, ACT_RELU);
    gemm_mfma_kernel<<<dim3(MB, 2), 256, 0, stream>>>(
        P0h, P0l, w_h1.h, w_h1.l, nullptr, nullptr, nullptr, nullptr,
        hh1_b, nullptr, P1h, P1l, qtab, qsc4,
        nullptr, nullptr, nullptr, N_NODES, 256, 256, ACT_LEAKY);

    // conv2 + hh2
    sage_mean_kernel<<<NB4, 256, 0, stream>>>(qtab, qsc4, off, csr_src, P2h, P2l);
    gemm_mfma_kernel<<<dim3(MB, 2), 256, 0, stream>>>(
        P2h, P2l, w_c2l.h, w_c2l.l, P1h, P1l, w_c2r.h, w_c2r.l,
        conv2_lb, nullptr, P0h, P0l, nullptr, nullptr,
        nullptr, nullptr, nullptr, N_NODES, 256, 256, ACT_RELU);
    gemm_mfma_kernel<<<dim3(MB, 2), 256, 0, stream>>>(
        P0h, P0l, w_h2.h, w_h2.l, nullptr, nullptr, nullptr, nullptr,
        hh2_b, nullptr, P1h, P1l, qtab, qsc4,
        nullptr, nullptr, nullptr, N_NODES, 256, 256, ACT_LEAKY);

    // conv3 (O=128) + oo (+ fused node dots in oo epilogue)
    sage_mean_kernel<<<NB4, 256, 0, stream>>>(qtab, qsc4, off, csr_src, P2h, P2l);
    gemm_mfma_kernel<<<dim3(MB, 1), 256, 0, stream>>>(
        P2h, P2l, w_c3l.h, w_c3l.l, P1h, P1l, w_c3r.h, w_c3r.l,
        conv3_lb, nullptr, P0h, P0l, nullptr, nullptr,
        nullptr, nullptr, nullptr, N_NODES, 256, 128, ACT_RELU);
    gemm_mfma_kernel<<<dim3(MB, 1), 256, 0, stream>>>(
        P0h, P0l, w_oo.h, w_oo.l, nullptr, nullptr, nullptr, nullptr,
        oo_b, nullptr, nullptr, nullptr, nullptr, nullptr,
        lin96_w, lin32_w, nodeDot, N_NODES, 128, 128, ACT_LEAKY);

    // fused per-edge affinity + 48-group mean
    const int G = N_EDGES / 48;
    edge_group_kernel<<<(G + 255) / 256, 256, 0, stream>>>(
        nodeDot, src, dst, edge_attr, lin96_b, lin32_b, (float*)d_out, G);
}